// Round 5
// baseline (167.469 us; speedup 1.0000x reference)
//
#include <hip/hip_runtime.h>
#include <hip/hip_bf16.h>

// ---------------------------------------------------------------------------
// HiddenEdgeDistanceMLP on MI355X (gfx950)
//
// reference:  s = s_lig[l] + s_poc[p]          [E,256]
//             h1 = silu(s @ W1.T + b1)         [E,128]
//             h2 = silu(h1 @ W2.T + b2)        [E,64]
//             out = relu(h2 @ W3.T + b3)       [E]
//
// Factorization: Z = concat(s_lig, s_poc) @ W1.T precomputed once (proj);
// b1 folded into ligand rows. Edge structure is block-diagonal and regular:
//   e = (b*32 + i)*160 + j,  l[e] = b*32+i,  p[e] = b*160+j
//
// edge_kernel v5: block = (b, 16-pocket chunk, ligand half) -> 2560 blocks,
// 4 waves x 4 ligand atoms. R4 counters: VALUBusy 53%, Occ 26% (~2 active
// waves/SIMD vs 6 permitted by VGPR=84) -> latency-bound; double the grid
// for TLP (mechanism validated R2->R3: grid 2x raised Occ 15->32%).
// NO min-waves bound (R3: (256,4) -> VGPR 64 -> spills). MFMA order: all-nt
// hi then all-nt lo per ks. pack_split truncates both terms (lo corrects hi
// exactly; v-hf Sterbenz-exact) -> absmax ~2e-3 vs 7.5e-3 threshold.
// ---------------------------------------------------------------------------

#define B_CPLX   128
#define NLB      32
#define NPB      160
#define SDIM     256
#define H1DIM    128
#define NL_TOT   (B_CPLX * NLB)         // 4096
#define NP_TOT   (B_CPLX * NPB)         // 20480
#define NROWS    (NL_TOT + NP_TOT)      // 24576
#define E_TOT    (B_CPLX * NLB * NPB)   // 655360

#define W1_LDS_STRIDE 264               // 256 + 8 bf16 pad
#define JT_CHUNK 16                     // pocket rows per block
#define ZP_STRIDE 132                   // 128 + 4 f32 pad

typedef __bf16 bf16x8 __attribute__((ext_vector_type(8)));
typedef unsigned short ushortx8 __attribute__((ext_vector_type(8)));
typedef unsigned short ushortx4 __attribute__((ext_vector_type(4)));
typedef float f32x4 __attribute__((ext_vector_type(4)));

__device__ __forceinline__ unsigned short f2bf(float f) {
    unsigned u = __builtin_bit_cast(unsigned, f);
    u += 0x7FFFu + ((u >> 16) & 1u);          // round-to-nearest-even
    return (unsigned short)(u >> 16);
}

// split x into hi = bf16_trunc(x), lo = bf16_trunc(x - hi).
// Truncation (not RNE) on hi is fine: lo corrects it; residual error 2^-16.
__device__ __forceinline__ void pack_split(const float* x, bf16x8& hi, bf16x8& lo) {
    ushortx8 uh, ul;
#pragma unroll
    for (int j = 0; j < 8; ++j) {
        float v = x[j];
        unsigned u = __builtin_bit_cast(unsigned, v);
        uh[j] = (unsigned short)(u >> 16);
        float hf = __builtin_bit_cast(float, u & 0xFFFF0000u);
        ul[j] = (unsigned short)(__builtin_bit_cast(unsigned, v - hf) >> 16);
    }
    hi = __builtin_bit_cast(bf16x8, uh);
    lo = __builtin_bit_cast(bf16x8, ul);
}

__device__ __forceinline__ bf16x8 pack8(const float* x) {
    ushortx8 us;
#pragma unroll
    for (int j = 0; j < 8; ++j) us[j] = f2bf(x[j]);
    return __builtin_bit_cast(bf16x8, us);
}

__device__ __forceinline__ float fast_silu(float x) {
    return x * __builtin_amdgcn_rcpf(1.0f + __expf(-x));
}

// ---------------------------------------------------------------------------
// Kernel 1: Z[m][n] = X[m] @ W1[n] (+ b1[n] if m is a ligand row)
// ---------------------------------------------------------------------------
__global__ __launch_bounds__(256) void proj_kernel(
    const float* __restrict__ s_lig, const float* __restrict__ s_poc,
    const float* __restrict__ W1,    const float* __restrict__ b1,
    float* __restrict__ Z)
{
    __shared__ unsigned short w1s[H1DIM * W1_LDS_STRIDE];   // 67.6 KB

    const int tid = threadIdx.x;
    {
        const f32x4* w4 = (const f32x4*)W1;     // 8192 f32x4 units
#pragma unroll
        for (int r = 0; r < 4; ++r) {
            f32x4 t[8];
#pragma unroll
            for (int s = 0; s < 8; ++s) t[s] = w4[tid + (r * 8 + s) * 256];
#pragma unroll
            for (int s = 0; s < 8; ++s) {
                const int u = tid + (r * 8 + s) * 256;
                const int n = u >> 6;
                const int k4 = u & 63;
                ushortx4 us;
#pragma unroll
                for (int j = 0; j < 4; ++j) us[j] = f2bf(t[s][j]);
                *(ushortx4*)(&w1s[n * W1_LDS_STRIDE + k4 * 4]) = us;
            }
        }
    }
    __syncthreads();

    const int lane = tid & 63;
    const int widx = tid >> 6;
    const int c    = lane & 15;
    const int q    = lane >> 4;
    const int tile = blockIdx.x * 4 + widx;       // 0..1535
    const int row  = tile * 16 + c;

    const float* src = (row < NL_TOT) ? (s_lig + (size_t)row * SDIM)
                                      : (s_poc + (size_t)(row - NL_TOT) * SDIM);

    f32x4 acc[8];
#pragma unroll
    for (int nt = 0; nt < 8; ++nt) acc[nt] = (f32x4){0.f, 0.f, 0.f, 0.f};

#pragma unroll
    for (int ks = 0; ks < 8; ++ks) {              // K = 256 = 8 x 32
        const int k0 = ks * 32 + q * 8;
        f32x4 xa = *reinterpret_cast<const f32x4*>(src + k0);
        f32x4 xb = *reinterpret_cast<const f32x4*>(src + k0 + 4);
        float xv[8] = {xa[0], xa[1], xa[2], xa[3], xb[0], xb[1], xb[2], xb[3]};
        bf16x8 ahi, alo;
        pack_split(xv, ahi, alo);
        bf16x8 bfrag[8];
#pragma unroll
        for (int nt = 0; nt < 8; ++nt)
            bfrag[nt] = *reinterpret_cast<const bf16x8*>(
                &w1s[(nt * 16 + c) * W1_LDS_STRIDE + k0]);
#pragma unroll
        for (int nt = 0; nt < 8; ++nt)            // hi pass (dep distance 8)
            acc[nt] = __builtin_amdgcn_mfma_f32_16x16x32_bf16(ahi, bfrag[nt], acc[nt], 0, 0, 0);
#pragma unroll
        for (int nt = 0; nt < 8; ++nt)            // lo pass
            acc[nt] = __builtin_amdgcn_mfma_f32_16x16x32_bf16(alo, bfrag[nt], acc[nt], 0, 0, 0);
    }

    // C/D layout: col n = lane&15, row m = q*4 + reg
    const int mb = tile * 16 + q * 4;
#pragma unroll
    for (int nt = 0; nt < 8; ++nt) {
        const int n = nt * 16 + c;
        const float bias = b1[n];
#pragma unroll
        for (int r = 0; r < 4; ++r) {
            const int m = mb + r;
            float v = acc[nt][r];
            if (m < NL_TOT) v += bias;            // fold b1 into ligand rows only
            Z[(size_t)m * H1DIM + n] = v;
        }
    }
}

// ---------------------------------------------------------------------------
// Kernel 2: block = (complex b, 16-pocket chunk jt, ligand half ih).
//   2560 blocks x 4 waves; each wave: 4 ligand atoms x 1 subtile of 16
//   edges. 16 pocket Z rows staged in LDS; W2 as B-frags in 64 VGPRs.
// ---------------------------------------------------------------------------
__global__ __launch_bounds__(256) void edge_kernel(
    const float* __restrict__ Z,
    const float* __restrict__ W2, const float* __restrict__ b2,
    const float* __restrict__ W3, const float* __restrict__ b3,
    float* __restrict__ out)
{
    __shared__ float zp[JT_CHUNK * ZP_STRIDE];    // 8.4 KB

    const int tid = threadIdx.x;
    const int bid = blockIdx.x;
    const int b   = bid / 20;
    const int rem = bid - b * 20;
    const int jt  = rem >> 1;                     // 0..9
    const int ih  = rem & 1;                      // ligand half

    // stage pocket rows: 16 rows x 128 f32 = 512 f32x4, 2 per thread
    {
        const float* zpg = Z + (size_t)(NL_TOT + b * NPB + jt * JT_CHUNK) * H1DIM;
#pragma unroll
        for (int s = 0; s < 2; ++s) {
            const int u   = tid + s * 256;
            const int row = u >> 5;
            const int c4  = u & 31;
            f32x4 v = *(const f32x4*)(zpg + (size_t)row * H1DIM + c4 * 4);
            *(f32x4*)(&zp[row * ZP_STRIDE + c4 * 4]) = v;
        }
    }

    const int lane = tid & 63;
    const int widx = tid >> 6;
    const int c    = lane & 15;
    const int q    = lane >> 4;

    // W2 B-frags: B[k][n] = W2[n][k]; n = nt*16 + c, k = ks*32 + q*8 + j
    bf16x8 w2f[4][4];
#pragma unroll
    for (int nt = 0; nt < 4; ++nt) {
        const float* wrow = W2 + (size_t)(nt * 16 + c) * H1DIM;
#pragma unroll
        for (int ks = 0; ks < 4; ++ks) {
            const int k0 = ks * 32 + q * 8;
            f32x4 wa = *reinterpret_cast<const f32x4*>(wrow + k0);
            f32x4 wb = *reinterpret_cast<const f32x4*>(wrow + k0 + 4);
            float wv[8] = {wa[0], wa[1], wa[2], wa[3], wb[0], wb[1], wb[2], wb[3]};
            w2f[nt][ks] = pack8(wv);
        }
    }
    float b2f[4], w3f[4];
#pragma unroll
    for (int nt = 0; nt < 4; ++nt) {
        b2f[nt] = b2[nt * 16 + c];
        w3f[nt] = W3[nt * 16 + c];
    }
    const float b3v = b3[0];

    __syncthreads();

    const float* lgbase = Z + (size_t)(b * NLB) * H1DIM;   // ligand rows of b
    const float* prow   = &zp[c * ZP_STRIDE];

    for (int ii = 0; ii < 4; ++ii) {
        const int i = widx * 8 + ih * 4 + ii;     // wave covers 4 of 32 atoms
        const float* lr = lgbase + (size_t)i * H1DIM;
        f32x4 lg[4][2];
#pragma unroll
        for (int ks = 0; ks < 4; ++ks) {
            const int k0 = ks * 32 + q * 8;
            lg[ks][0] = *(const f32x4*)(lr + k0);
            lg[ks][1] = *(const f32x4*)(lr + k0 + 4);
        }

        f32x4 acc[4];
#pragma unroll
        for (int nt = 0; nt < 4; ++nt) acc[nt] = (f32x4){0.f, 0.f, 0.f, 0.f};

#pragma unroll
        for (int ks = 0; ks < 4; ++ks) {           // K = 128 = 4 x 32
            const int k0 = ks * 32 + q * 8;
            f32x4 pa = *(const f32x4*)(prow + k0);
            f32x4 pb = *(const f32x4*)(prow + k0 + 4);
            float hv[8];
#pragma unroll
            for (int j = 0; j < 4; ++j) {
                hv[j]     = fast_silu(pa[j] + lg[ks][0][j]);
                hv[4 + j] = fast_silu(pb[j] + lg[ks][1][j]);
            }
            bf16x8 ahi, alo;
            pack_split(hv, ahi, alo);
#pragma unroll
            for (int nt = 0; nt < 4; ++nt)         // hi pass (dep distance 4)
                acc[nt] = __builtin_amdgcn_mfma_f32_16x16x32_bf16(ahi, w2f[nt][ks], acc[nt], 0, 0, 0);
#pragma unroll
            for (int nt = 0; nt < 4; ++nt)         // lo pass
                acc[nt] = __builtin_amdgcn_mfma_f32_16x16x32_bf16(alo, w2f[nt][ks], acc[nt], 0, 0, 0);
        }

        // epilogue: lane holds D[m = q*4 + r][n = nt*16 + c]
        float s0 = 0.f, s1 = 0.f, s2 = 0.f, s3 = 0.f;
#pragma unroll
        for (int nt = 0; nt < 4; ++nt) {
            s0 += fast_silu(acc[nt][0] + b2f[nt]) * w3f[nt];
            s1 += fast_silu(acc[nt][1] + b2f[nt]) * w3f[nt];
            s2 += fast_silu(acc[nt][2] + b2f[nt]) * w3f[nt];
            s3 += fast_silu(acc[nt][3] + b2f[nt]) * w3f[nt];
        }
#pragma unroll
        for (int m = 1; m < 16; m <<= 1) {         // reduce over n (16-lane groups)
            s0 += __shfl_xor(s0, m, 64);
            s1 += __shfl_xor(s1, m, 64);
            s2 += __shfl_xor(s2, m, 64);
            s3 += __shfl_xor(s3, m, 64);
        }
        if (c < 4) {
            float v = (c == 0) ? s0 : (c == 1) ? s1 : (c == 2) ? s2 : s3;
            const int e0 = (b * NLB + i) * NPB + jt * JT_CHUNK;
            out[e0 + q * 4 + c] = fmaxf(v + b3v, 0.0f);
        }
    }
}

// ---------------------------------------------------------------------------
extern "C" void kernel_launch(void* const* d_in, const int* in_sizes, int n_in,
                              void* d_out, int out_size, void* d_ws, size_t ws_size,
                              hipStream_t stream)
{
    const float* s_lig = (const float*)d_in[0];
    const float* s_poc = (const float*)d_in[1];
    const float* W1    = (const float*)d_in[4];
    const float* b1    = (const float*)d_in[5];
    const float* W2    = (const float*)d_in[6];
    const float* b2    = (const float*)d_in[7];
    const float* W3    = (const float*)d_in[8];
    const float* b3    = (const float*)d_in[9];

    float* Z = (float*)d_ws;   // NROWS*H1DIM*4 = 12.58 MB workspace

    hipLaunchKernelGGL(proj_kernel, dim3(NROWS / 16 / 4), dim3(256), 0, stream,
                       s_lig, s_poc, W1, b1, Z);
    hipLaunchKernelGGL(edge_kernel, dim3(B_CPLX * 20), dim3(256), 0, stream,
                       Z, W2, b2, W3, b3, (float*)d_out);
}

// Round 6
// 157.105 us; speedup vs baseline: 1.0660x; 1.0660x over previous
//
#include <hip/hip_runtime.h>
#include <hip/hip_bf16.h>

// ---------------------------------------------------------------------------
// HiddenEdgeDistanceMLP on MI355X (gfx950)
//
// reference:  s = s_lig[l] + s_poc[p]          [E,256]
//             h1 = silu(s @ W1.T + b1)         [E,128]
//             h2 = silu(h1 @ W2.T + b2)        [E,64]
//             out = relu(h2 @ W3.T + b3)       [E]
//
// Factorization: Z = concat(s_lig, s_poc) @ W1.T precomputed once (proj);
// b1 folded into ligand rows. Edge structure is block-diagonal and regular:
//   e = (b*32 + i)*160 + j,  l[e] = b*32+i,  p[e] = b*160+j
//
// edge_kernel v6: R4 grid (1280 blocks = (b, 16-pocket chunk), 4 waves x
// 8 ligand atoms — best measured; R5's 2x grid regressed). NEW: W2 staged
// as pre-packed bf16 B-FRAGMENTS in LDS, fragment-ordered so the K-loop
// reads each frag with one conflict-free immediate-offset ds_read_b128
// (shared by hi+lo MFMA). Rationale: holding w2f in regs needs 64 VGPRs;
// at VGPR=84 the compiler rematerialized them as per-atom GLOBAL loads
// (L2 latency in the K-loop) -> the R4 latency wall. Now the K-loop is
// LDS/VALU/MFMA only. NO min-waves bound (R3: VGPR 64 -> spills).
// pack_split truncates both terms (lo corrects hi; Sterbenz-exact) ->
// absmax ~2e-3 vs 7.5e-3 threshold.
// ---------------------------------------------------------------------------

#define B_CPLX   128
#define NLB      32
#define NPB      160
#define SDIM     256
#define H1DIM    128
#define NL_TOT   (B_CPLX * NLB)         // 4096
#define NP_TOT   (B_CPLX * NPB)         // 20480
#define NROWS    (NL_TOT + NP_TOT)      // 24576
#define E_TOT    (B_CPLX * NLB * NPB)   // 655360

#define W1_LDS_STRIDE 264               // 256 + 8 bf16 pad
#define JT_CHUNK 16                     // pocket rows per block
#define ZP_STRIDE 132                   // 128 + 4 f32 pad

typedef __bf16 bf16x8 __attribute__((ext_vector_type(8)));
typedef unsigned short ushortx8 __attribute__((ext_vector_type(8)));
typedef unsigned short ushortx4 __attribute__((ext_vector_type(4)));
typedef float f32x4 __attribute__((ext_vector_type(4)));

__device__ __forceinline__ unsigned short f2bf(float f) {
    unsigned u = __builtin_bit_cast(unsigned, f);
    u += 0x7FFFu + ((u >> 16) & 1u);          // round-to-nearest-even
    return (unsigned short)(u >> 16);
}

// split x into hi = bf16_trunc(x), lo = bf16_trunc(x - hi).
// Truncation (not RNE) on hi is fine: lo corrects it; residual error 2^-16.
__device__ __forceinline__ void pack_split(const float* x, bf16x8& hi, bf16x8& lo) {
    ushortx8 uh, ul;
#pragma unroll
    for (int j = 0; j < 8; ++j) {
        float v = x[j];
        unsigned u = __builtin_bit_cast(unsigned, v);
        uh[j] = (unsigned short)(u >> 16);
        float hf = __builtin_bit_cast(float, u & 0xFFFF0000u);
        ul[j] = (unsigned short)(__builtin_bit_cast(unsigned, v - hf) >> 16);
    }
    hi = __builtin_bit_cast(bf16x8, uh);
    lo = __builtin_bit_cast(bf16x8, ul);
}

__device__ __forceinline__ float fast_silu(float x) {
    return x * __builtin_amdgcn_rcpf(1.0f + __expf(-x));
}

// ---------------------------------------------------------------------------
// Kernel 1: Z[m][n] = X[m] @ W1[n] (+ b1[n] if m is a ligand row)
// ---------------------------------------------------------------------------
__global__ __launch_bounds__(256) void proj_kernel(
    const float* __restrict__ s_lig, const float* __restrict__ s_poc,
    const float* __restrict__ W1,    const float* __restrict__ b1,
    float* __restrict__ Z)
{
    __shared__ unsigned short w1s[H1DIM * W1_LDS_STRIDE];   // 67.6 KB

    const int tid = threadIdx.x;
    {
        const f32x4* w4 = (const f32x4*)W1;     // 8192 f32x4 units
#pragma unroll
        for (int r = 0; r < 4; ++r) {
            f32x4 t[8];
#pragma unroll
            for (int s = 0; s < 8; ++s) t[s] = w4[tid + (r * 8 + s) * 256];
#pragma unroll
            for (int s = 0; s < 8; ++s) {
                const int u = tid + (r * 8 + s) * 256;
                const int n = u >> 6;
                const int k4 = u & 63;
                ushortx4 us;
#pragma unroll
                for (int j = 0; j < 4; ++j) us[j] = f2bf(t[s][j]);
                *(ushortx4*)(&w1s[n * W1_LDS_STRIDE + k4 * 4]) = us;
            }
        }
    }
    __syncthreads();

    const int lane = tid & 63;
    const int widx = tid >> 6;
    const int c    = lane & 15;
    const int q    = lane >> 4;
    const int tile = blockIdx.x * 4 + widx;       // 0..1535
    const int row  = tile * 16 + c;

    const float* src = (row < NL_TOT) ? (s_lig + (size_t)row * SDIM)
                                      : (s_poc + (size_t)(row - NL_TOT) * SDIM);

    f32x4 acc[8];
#pragma unroll
    for (int nt = 0; nt < 8; ++nt) acc[nt] = (f32x4){0.f, 0.f, 0.f, 0.f};

#pragma unroll
    for (int ks = 0; ks < 8; ++ks) {              // K = 256 = 8 x 32
        const int k0 = ks * 32 + q * 8;
        f32x4 xa = *reinterpret_cast<const f32x4*>(src + k0);
        f32x4 xb = *reinterpret_cast<const f32x4*>(src + k0 + 4);
        float xv[8] = {xa[0], xa[1], xa[2], xa[3], xb[0], xb[1], xb[2], xb[3]};
        bf16x8 ahi, alo;
        pack_split(xv, ahi, alo);
        bf16x8 bfrag[8];
#pragma unroll
        for (int nt = 0; nt < 8; ++nt)
            bfrag[nt] = *reinterpret_cast<const bf16x8*>(
                &w1s[(nt * 16 + c) * W1_LDS_STRIDE + k0]);
#pragma unroll
        for (int nt = 0; nt < 8; ++nt)            // hi pass (dep distance 8)
            acc[nt] = __builtin_amdgcn_mfma_f32_16x16x32_bf16(ahi, bfrag[nt], acc[nt], 0, 0, 0);
#pragma unroll
        for (int nt = 0; nt < 8; ++nt)            // lo pass
            acc[nt] = __builtin_amdgcn_mfma_f32_16x16x32_bf16(alo, bfrag[nt], acc[nt], 0, 0, 0);
    }

    // C/D layout: col n = lane&15, row m = q*4 + reg
    const int mb = tile * 16 + q * 4;
#pragma unroll
    for (int nt = 0; nt < 8; ++nt) {
        const int n = nt * 16 + c;
        const float bias = b1[n];
#pragma unroll
        for (int r = 0; r < 4; ++r) {
            const int m = mb + r;
            float v = acc[nt][r];
            if (m < NL_TOT) v += bias;            // fold b1 into ligand rows only
            Z[(size_t)m * H1DIM + n] = v;
        }
    }
}

// ---------------------------------------------------------------------------
// Kernel 2: block = (complex b, 16-pocket chunk jt). 1280 blocks x 4 waves,
//   8 ligand atoms per wave. Pocket Z rows + pre-packed W2 B-frags in LDS.
//   K-loop: ds_read-only operands, no global traffic.
// ---------------------------------------------------------------------------
__global__ __launch_bounds__(256) void edge_kernel(
    const float* __restrict__ Z,
    const float* __restrict__ W2, const float* __restrict__ b2,
    const float* __restrict__ W3, const float* __restrict__ b3,
    float* __restrict__ out)
{
    __shared__ float zp[JT_CHUNK * ZP_STRIDE];            // 8.4 KB
    __shared__ unsigned short w2s[16 * 64 * 8];           // 16 KB frag-ordered

    const int tid = threadIdx.x;
    const int bid = blockIdx.x;
    const int b   = bid / 10;
    const int jt  = bid - b * 10;

    // stage pocket rows: 16 rows x 128 f32 = 512 f32x4, 2 per thread
    {
        const float* zpg = Z + (size_t)(NL_TOT + b * NPB + jt * JT_CHUNK) * H1DIM;
#pragma unroll
        for (int s = 0; s < 2; ++s) {
            const int u   = tid + s * 256;
            const int row = u >> 5;
            const int c4  = u & 31;
            f32x4 v = *(const f32x4*)(zpg + (size_t)row * H1DIM + c4 * 4);
            *(f32x4*)(&zp[row * ZP_STRIDE + c4 * 4]) = v;
        }
    }

    // stage W2 as bf16 B-fragments, fragment-ordered:
    //   slot = chunk*64 + lane, chunk = nt*4 + ks;
    //   frag(lane) = W2[n = nt*16 + (lane&15)][ks*32 + (lane>>4)*8 .. +8]
    //   -> reader does ds_read_b128 at lane*16 + chunk*1024 (conflict-free)
    {
#pragma unroll
        for (int s = 0; s < 4; ++s) {
            const int slot   = tid + s * 256;             // 0..1023
            const int lane_s = slot & 63;
            const int chunk  = slot >> 6;
            const int nt     = chunk >> 2;
            const int ks     = chunk & 3;
            const int n      = nt * 16 + (lane_s & 15);
            const int k0     = ks * 32 + (lane_s >> 4) * 8;
            const float* wsrc = W2 + (size_t)n * H1DIM + k0;
            f32x4 wa = *(const f32x4*)wsrc;
            f32x4 wb = *(const f32x4*)(wsrc + 4);
            float wv[8] = {wa[0], wa[1], wa[2], wa[3], wb[0], wb[1], wb[2], wb[3]};
            ushortx8 us;
#pragma unroll
            for (int j = 0; j < 8; ++j) us[j] = f2bf(wv[j]);   // RNE for weights
            *(ushortx8*)(&w2s[slot * 8]) = us;
        }
    }

    const int lane = tid & 63;
    const int widx = tid >> 6;
    const int c    = lane & 15;
    const int q    = lane >> 4;

    float b2f[4], w3f[4];
#pragma unroll
    for (int nt = 0; nt < 4; ++nt) {
        b2f[nt] = b2[nt * 16 + c];
        w3f[nt] = W3[nt * 16 + c];
    }
    const float b3v = b3[0];

    __syncthreads();

    const float* lgbase = Z + (size_t)(b * NLB) * H1DIM;   // ligand rows of b
    const float* prow   = &zp[c * ZP_STRIDE];
    const unsigned short* wbase = &w2s[lane * 8];          // + chunk*512 ushorts

    for (int ii = 0; ii < 8; ++ii) {
        const int i = widx * 8 + ii;
        const float* lr = lgbase + (size_t)i * H1DIM;
        f32x4 lg[4][2];
#pragma unroll
        for (int ks = 0; ks < 4; ++ks) {
            const int k0 = ks * 32 + q * 8;
            lg[ks][0] = *(const f32x4*)(lr + k0);
            lg[ks][1] = *(const f32x4*)(lr + k0 + 4);
        }

        f32x4 acc[4];
#pragma unroll
        for (int nt = 0; nt < 4; ++nt) acc[nt] = (f32x4){0.f, 0.f, 0.f, 0.f};

#pragma unroll
        for (int ks = 0; ks < 4; ++ks) {           // K = 128 = 4 x 32
            const int k0 = ks * 32 + q * 8;
            f32x4 pa = *(const f32x4*)(prow + k0);
            f32x4 pb = *(const f32x4*)(prow + k0 + 4);
            float hv[8];
#pragma unroll
            for (int j = 0; j < 4; ++j) {
                hv[j]     = fast_silu(pa[j] + lg[ks][0][j]);
                hv[4 + j] = fast_silu(pb[j] + lg[ks][1][j]);
            }
            bf16x8 ahi, alo;
            pack_split(hv, ahi, alo);
            bf16x8 bfr[4];
#pragma unroll
            for (int nt = 0; nt < 4; ++nt)         // conflict-free ds_read_b128
                bfr[nt] = *(const bf16x8*)(wbase + (nt * 4 + ks) * 512);
#pragma unroll
            for (int nt = 0; nt < 4; ++nt)         // hi pass (dep distance 4)
                acc[nt] = __builtin_amdgcn_mfma_f32_16x16x32_bf16(ahi, bfr[nt], acc[nt], 0, 0, 0);
#pragma unroll
            for (int nt = 0; nt < 4; ++nt)         // lo pass
                acc[nt] = __builtin_amdgcn_mfma_f32_16x16x32_bf16(alo, bfr[nt], acc[nt], 0, 0, 0);
        }

        // epilogue: lane holds D[m = q*4 + r][n = nt*16 + c]
        float s0 = 0.f, s1 = 0.f, s2 = 0.f, s3 = 0.f;
#pragma unroll
        for (int nt = 0; nt < 4; ++nt) {
            s0 += fast_silu(acc[nt][0] + b2f[nt]) * w3f[nt];
            s1 += fast_silu(acc[nt][1] + b2f[nt]) * w3f[nt];
            s2 += fast_silu(acc[nt][2] + b2f[nt]) * w3f[nt];
            s3 += fast_silu(acc[nt][3] + b2f[nt]) * w3f[nt];
        }
#pragma unroll
        for (int m = 1; m < 16; m <<= 1) {         // reduce over n (16-lane groups)
            s0 += __shfl_xor(s0, m, 64);
            s1 += __shfl_xor(s1, m, 64);
            s2 += __shfl_xor(s2, m, 64);
            s3 += __shfl_xor(s3, m, 64);
        }
        if (c < 4) {
            float v = (c == 0) ? s0 : (c == 1) ? s1 : (c == 2) ? s2 : s3;
            const int e0 = (b * NLB + i) * NPB + jt * JT_CHUNK;
            out[e0 + q * 4 + c] = fmaxf(v + b3v, 0.0f);
        }
    }
}

// ---------------------------------------------------------------------------
extern "C" void kernel_launch(void* const* d_in, const int* in_sizes, int n_in,
                              void* d_out, int out_size, void* d_ws, size_t ws_size,
                              hipStream_t stream)
{
    const float* s_lig = (const float*)d_in[0];
    const float* s_poc = (const float*)d_in[1];
    const float* W1    = (const float*)d_in[4];
    const float* b1    = (const float*)d_in[5];
    const float* W2    = (const float*)d_in[6];
    const float* b2    = (const float*)d_in[7];
    const float* W3    = (const float*)d_in[8];
    const float* b3    = (const float*)d_in[9];

    float* Z = (float*)d_ws;   // NROWS*H1DIM*4 = 12.58 MB workspace

    hipLaunchKernelGGL(proj_kernel, dim3(NROWS / 16 / 4), dim3(256), 0, stream,
                       s_lig, s_poc, W1, b1, Z);
    hipLaunchKernelGGL(edge_kernel, dim3(B_CPLX * 10), dim3(256), 0, stream,
                       Z, W2, b2, W3, b3, (float*)d_out);
}

// Round 7
// 143.619 us; speedup vs baseline: 1.1661x; 1.0939x over previous
//
#include <hip/hip_runtime.h>
#include <hip/hip_bf16.h>

// ---------------------------------------------------------------------------
// HiddenEdgeDistanceMLP on MI355X (gfx950)
//
// reference:  s = s_lig[l] + s_poc[p]          [E,256]
//             h1 = silu(s @ W1.T + b1)         [E,128]
//             h2 = silu(h1 @ W2.T + b2)        [E,64]
//             out = relu(h2 @ W3.T + b3)       [E]
//
// Factorization: Z = concat(s_lig, s_poc) @ W1.T precomputed once (proj);
// b1 folded into ligand rows. Edge structure is block-diagonal and regular:
//   e = (b*32 + i)*160 + j,  l[e] = b*32+i,  p[e] = b*160+j
//
// edge_kernel v7: R6 structure (1280 blocks = (b, 16-pocket chunk), 4 waves
// x 8 atoms, pocket rows + pre-packed W2 B-frags in LDS) + software
// pipelining: atom ii+1's 8 ligand global loads are issued between atom
// ii's K-loop and epilogue, so the ~400-cyc epilogue (h2 silu + butterfly
// + store) hides the VMEM latency instead of an exposed vmcnt(0) stall at
// each atom top. W2-frag ds_reads + pocket ds_reads hoisted ahead of the
// silu chain in each ks body. Register peak during K-loop unchanged
// (prefetch regs live only through the epilogue) — avoids R3's VGPR cliff.
// pack_split truncates both terms (lo corrects hi; Sterbenz-exact) ->
// absmax ~2e-3 vs 7.5e-3 threshold.
// ---------------------------------------------------------------------------

#define B_CPLX   128
#define NLB      32
#define NPB      160
#define SDIM     256
#define H1DIM    128
#define NL_TOT   (B_CPLX * NLB)         // 4096
#define NP_TOT   (B_CPLX * NPB)         // 20480
#define NROWS    (NL_TOT + NP_TOT)      // 24576
#define E_TOT    (B_CPLX * NLB * NPB)   // 655360

#define W1_LDS_STRIDE 264               // 256 + 8 bf16 pad
#define JT_CHUNK 16                     // pocket rows per block
#define ZP_STRIDE 132                   // 128 + 4 f32 pad

typedef __bf16 bf16x8 __attribute__((ext_vector_type(8)));
typedef unsigned short ushortx8 __attribute__((ext_vector_type(8)));
typedef unsigned short ushortx4 __attribute__((ext_vector_type(4)));
typedef float f32x4 __attribute__((ext_vector_type(4)));

__device__ __forceinline__ unsigned short f2bf(float f) {
    unsigned u = __builtin_bit_cast(unsigned, f);
    u += 0x7FFFu + ((u >> 16) & 1u);          // round-to-nearest-even
    return (unsigned short)(u >> 16);
}

// split x into hi = bf16_trunc(x), lo = bf16_trunc(x - hi).
// Truncation (not RNE) on hi is fine: lo corrects it; residual error 2^-16.
__device__ __forceinline__ void pack_split(const float* x, bf16x8& hi, bf16x8& lo) {
    ushortx8 uh, ul;
#pragma unroll
    for (int j = 0; j < 8; ++j) {
        float v = x[j];
        unsigned u = __builtin_bit_cast(unsigned, v);
        uh[j] = (unsigned short)(u >> 16);
        float hf = __builtin_bit_cast(float, u & 0xFFFF0000u);
        ul[j] = (unsigned short)(__builtin_bit_cast(unsigned, v - hf) >> 16);
    }
    hi = __builtin_bit_cast(bf16x8, uh);
    lo = __builtin_bit_cast(bf16x8, ul);
}

__device__ __forceinline__ float fast_silu(float x) {
    return x * __builtin_amdgcn_rcpf(1.0f + __expf(-x));
}

// ---------------------------------------------------------------------------
// Kernel 1: Z[m][n] = X[m] @ W1[n] (+ b1[n] if m is a ligand row)
// ---------------------------------------------------------------------------
__global__ __launch_bounds__(256) void proj_kernel(
    const float* __restrict__ s_lig, const float* __restrict__ s_poc,
    const float* __restrict__ W1,    const float* __restrict__ b1,
    float* __restrict__ Z)
{
    __shared__ unsigned short w1s[H1DIM * W1_LDS_STRIDE];   // 67.6 KB

    const int tid = threadIdx.x;
    {
        const f32x4* w4 = (const f32x4*)W1;     // 8192 f32x4 units
#pragma unroll
        for (int r = 0; r < 4; ++r) {
            f32x4 t[8];
#pragma unroll
            for (int s = 0; s < 8; ++s) t[s] = w4[tid + (r * 8 + s) * 256];
#pragma unroll
            for (int s = 0; s < 8; ++s) {
                const int u = tid + (r * 8 + s) * 256;
                const int n = u >> 6;
                const int k4 = u & 63;
                ushortx4 us;
#pragma unroll
                for (int j = 0; j < 4; ++j) us[j] = f2bf(t[s][j]);
                *(ushortx4*)(&w1s[n * W1_LDS_STRIDE + k4 * 4]) = us;
            }
        }
    }
    __syncthreads();

    const int lane = tid & 63;
    const int widx = tid >> 6;
    const int c    = lane & 15;
    const int q    = lane >> 4;
    const int tile = blockIdx.x * 4 + widx;       // 0..1535
    const int row  = tile * 16 + c;

    const float* src = (row < NL_TOT) ? (s_lig + (size_t)row * SDIM)
                                      : (s_poc + (size_t)(row - NL_TOT) * SDIM);

    f32x4 acc[8];
#pragma unroll
    for (int nt = 0; nt < 8; ++nt) acc[nt] = (f32x4){0.f, 0.f, 0.f, 0.f};

#pragma unroll
    for (int ks = 0; ks < 8; ++ks) {              // K = 256 = 8 x 32
        const int k0 = ks * 32 + q * 8;
        f32x4 xa = *reinterpret_cast<const f32x4*>(src + k0);
        f32x4 xb = *reinterpret_cast<const f32x4*>(src + k0 + 4);
        float xv[8] = {xa[0], xa[1], xa[2], xa[3], xb[0], xb[1], xb[2], xb[3]};
        bf16x8 ahi, alo;
        pack_split(xv, ahi, alo);
        bf16x8 bfrag[8];
#pragma unroll
        for (int nt = 0; nt < 8; ++nt)
            bfrag[nt] = *reinterpret_cast<const bf16x8*>(
                &w1s[(nt * 16 + c) * W1_LDS_STRIDE + k0]);
#pragma unroll
        for (int nt = 0; nt < 8; ++nt)            // hi pass (dep distance 8)
            acc[nt] = __builtin_amdgcn_mfma_f32_16x16x32_bf16(ahi, bfrag[nt], acc[nt], 0, 0, 0);
#pragma unroll
        for (int nt = 0; nt < 8; ++nt)            // lo pass
            acc[nt] = __builtin_amdgcn_mfma_f32_16x16x32_bf16(alo, bfrag[nt], acc[nt], 0, 0, 0);
    }

    // C/D layout: col n = lane&15, row m = q*4 + reg
    const int mb = tile * 16 + q * 4;
#pragma unroll
    for (int nt = 0; nt < 8; ++nt) {
        const int n = nt * 16 + c;
        const float bias = b1[n];
#pragma unroll
        for (int r = 0; r < 4; ++r) {
            const int m = mb + r;
            float v = acc[nt][r];
            if (m < NL_TOT) v += bias;            // fold b1 into ligand rows only
            Z[(size_t)m * H1DIM + n] = v;
        }
    }
}

// ---------------------------------------------------------------------------
// Kernel 2: block = (complex b, 16-pocket chunk jt). 1280 blocks x 4 waves,
//   8 ligand atoms per wave, ligand loads software-pipelined across atoms.
// ---------------------------------------------------------------------------
__global__ __launch_bounds__(256) void edge_kernel(
    const float* __restrict__ Z,
    const float* __restrict__ W2, const float* __restrict__ b2,
    const float* __restrict__ W3, const float* __restrict__ b3,
    float* __restrict__ out)
{
    __shared__ float zp[JT_CHUNK * ZP_STRIDE];            // 8.4 KB
    __shared__ unsigned short w2s[16 * 64 * 8];           // 16 KB frag-ordered

    const int tid = threadIdx.x;
    const int bid = blockIdx.x;
    const int b   = bid / 10;
    const int jt  = bid - b * 10;

    // stage pocket rows: 16 rows x 128 f32 = 512 f32x4, 2 per thread
    {
        const float* zpg = Z + (size_t)(NL_TOT + b * NPB + jt * JT_CHUNK) * H1DIM;
#pragma unroll
        for (int s = 0; s < 2; ++s) {
            const int u   = tid + s * 256;
            const int row = u >> 5;
            const int c4  = u & 31;
            f32x4 v = *(const f32x4*)(zpg + (size_t)row * H1DIM + c4 * 4);
            *(f32x4*)(&zp[row * ZP_STRIDE + c4 * 4]) = v;
        }
    }

    // stage W2 as bf16 B-fragments, fragment-ordered:
    //   slot = chunk*64 + lane, chunk = nt*4 + ks;
    //   frag(lane) = W2[n = nt*16 + (lane&15)][ks*32 + (lane>>4)*8 .. +8]
    //   -> reader does ds_read_b128 at lane*16 + chunk*1024 (conflict-free)
    {
#pragma unroll
        for (int s = 0; s < 4; ++s) {
            const int slot   = tid + s * 256;             // 0..1023
            const int lane_s = slot & 63;
            const int chunk  = slot >> 6;
            const int nt     = chunk >> 2;
            const int ks     = chunk & 3;
            const int n      = nt * 16 + (lane_s & 15);
            const int k0     = ks * 32 + (lane_s >> 4) * 8;
            const float* wsrc = W2 + (size_t)n * H1DIM + k0;
            f32x4 wa = *(const f32x4*)wsrc;
            f32x4 wb = *(const f32x4*)(wsrc + 4);
            float wv[8] = {wa[0], wa[1], wa[2], wa[3], wb[0], wb[1], wb[2], wb[3]};
            ushortx8 us;
#pragma unroll
            for (int j = 0; j < 8; ++j) us[j] = f2bf(wv[j]);   // RNE for weights
            *(ushortx8*)(&w2s[slot * 8]) = us;
        }
    }

    const int lane = tid & 63;
    const int widx = tid >> 6;
    const int c    = lane & 15;
    const int q    = lane >> 4;

    float b2f[4], w3f[4];
#pragma unroll
    for (int nt = 0; nt < 4; ++nt) {
        b2f[nt] = b2[nt * 16 + c];
        w3f[nt] = W3[nt * 16 + c];
    }
    const float b3v = b3[0];

    __syncthreads();

    const float* lgbase = Z + (size_t)(b * NLB) * H1DIM;   // ligand rows of b
    const float* prow   = &zp[c * ZP_STRIDE];
    const unsigned short* wbase = &w2s[lane * 8];          // + chunk*512 ushorts

    // prologue: load atom 0's ligand fragment
    f32x4 lg[4][2];
    {
        const float* lr0 = lgbase + (size_t)(widx * 8) * H1DIM;
#pragma unroll
        for (int ks = 0; ks < 4; ++ks) {
            const int k0 = ks * 32 + q * 8;
            lg[ks][0] = *(const f32x4*)(lr0 + k0);
            lg[ks][1] = *(const f32x4*)(lr0 + k0 + 4);
        }
    }

    for (int ii = 0; ii < 8; ++ii) {
        const int i = widx * 8 + ii;

        f32x4 acc[4];
#pragma unroll
        for (int nt = 0; nt < 4; ++nt) acc[nt] = (f32x4){0.f, 0.f, 0.f, 0.f};

#pragma unroll
        for (int ks = 0; ks < 4; ++ks) {           // K = 128 = 4 x 32
            const int k0 = ks * 32 + q * 8;
            // hoist all LDS reads for this ks ahead of the VALU chain
            bf16x8 bfr[4];
#pragma unroll
            for (int nt = 0; nt < 4; ++nt)         // conflict-free ds_read_b128
                bfr[nt] = *(const bf16x8*)(wbase + (nt * 4 + ks) * 512);
            f32x4 pa = *(const f32x4*)(prow + k0);
            f32x4 pb = *(const f32x4*)(prow + k0 + 4);
            float hv[8];
#pragma unroll
            for (int j = 0; j < 4; ++j) {
                hv[j]     = fast_silu(pa[j] + lg[ks][0][j]);
                hv[4 + j] = fast_silu(pb[j] + lg[ks][1][j]);
            }
            bf16x8 ahi, alo;
            pack_split(hv, ahi, alo);
#pragma unroll
            for (int nt = 0; nt < 4; ++nt)         // hi pass (dep distance 4)
                acc[nt] = __builtin_amdgcn_mfma_f32_16x16x32_bf16(ahi, bfr[nt], acc[nt], 0, 0, 0);
#pragma unroll
            for (int nt = 0; nt < 4; ++nt)         // lo pass
                acc[nt] = __builtin_amdgcn_mfma_f32_16x16x32_bf16(alo, bfr[nt], acc[nt], 0, 0, 0);
        }

        // prefetch next atom's ligand fragment; the epilogue below (~400 cyc)
        // hides the VMEM latency. (ii+1)&7 wraps to a valid row on the last
        // iteration so this stays branchless.
        f32x4 lgN[4][2];
        {
            const float* lrn = lgbase + (size_t)(widx * 8 + ((ii + 1) & 7)) * H1DIM;
#pragma unroll
            for (int ks = 0; ks < 4; ++ks) {
                const int k0 = ks * 32 + q * 8;
                lgN[ks][0] = *(const f32x4*)(lrn + k0);
                lgN[ks][1] = *(const f32x4*)(lrn + k0 + 4);
            }
        }

        // epilogue: lane holds D[m = q*4 + r][n = nt*16 + c]
        float s0 = 0.f, s1 = 0.f, s2 = 0.f, s3 = 0.f;
#pragma unroll
        for (int nt = 0; nt < 4; ++nt) {
            s0 += fast_silu(acc[nt][0] + b2f[nt]) * w3f[nt];
            s1 += fast_silu(acc[nt][1] + b2f[nt]) * w3f[nt];
            s2 += fast_silu(acc[nt][2] + b2f[nt]) * w3f[nt];
            s3 += fast_silu(acc[nt][3] + b2f[nt]) * w3f[nt];
        }
#pragma unroll
        for (int m = 1; m < 16; m <<= 1) {         // reduce over n (16-lane groups)
            s0 += __shfl_xor(s0, m, 64);
            s1 += __shfl_xor(s1, m, 64);
            s2 += __shfl_xor(s2, m, 64);
            s3 += __shfl_xor(s3, m, 64);
        }
        if (c < 4) {
            float v = (c == 0) ? s0 : (c == 1) ? s1 : (c == 2) ? s2 : s3;
            const int e0 = (b * NLB + i) * NPB + jt * JT_CHUNK;
            out[e0 + q * 4 + c] = fmaxf(v + b3v, 0.0f);
        }

#pragma unroll
        for (int ks = 0; ks < 4; ++ks) {           // rotate prefetch buffer
            lg[ks][0] = lgN[ks][0];
            lg[ks][1] = lgN[ks][1];
        }
    }
}

// ---------------------------------------------------------------------------
extern "C" void kernel_launch(void* const* d_in, const int* in_sizes, int n_in,
                              void* d_out, int out_size, void* d_ws, size_t ws_size,
                              hipStream_t stream)
{
    const float* s_lig = (const float*)d_in[0];
    const float* s_poc = (const float*)d_in[1];
    const float* W1    = (const float*)d_in[4];
    const float* b1    = (const float*)d_in[5];
    const float* W2    = (const float*)d_in[6];
    const float* b2    = (const float*)d_in[7];
    const float* W3    = (const float*)d_in[8];
    const float* b3    = (const float*)d_in[9];

    float* Z = (float*)d_ws;   // NROWS*H1DIM*4 = 12.58 MB workspace

    hipLaunchKernelGGL(proj_kernel, dim3(NROWS / 16 / 4), dim3(256), 0, stream,
                       s_lig, s_poc, W1, b1, Z);
    hipLaunchKernelGGL(edge_kernel, dim3(B_CPLX * 10), dim3(256), 0, stream,
                       Z, W2, b2, W3, b3, (float*)d_out);
}